// Round 1
// baseline (374.668 us; speedup 1.0000x reference)
//
#include <hip/hip_runtime.h>
#include <hip/hip_bf16.h>

#define RFn 500000
#define F1n 256
#define NFn 128
#define RAn 50000
#define LN_EPSn 1e-5f

typedef float f32x4 __attribute__((ext_vector_type(4)));
typedef short short8 __attribute__((ext_vector_type(8)));

__device__ __forceinline__ short f2bf(float f) {
  __hip_bfloat16 h = __float2bfloat16(f);  // RNE
  return __builtin_bit_cast(short, h);
}

// ---------------------------------------------------------------------------
// Prep: pack W_feat (256x128 f32, row-major [k][col]) into MFMA B-fragment
// image: 64 frags (s=0..7 k-steps, c=0..7 col-tiles), each frag = 64 lanes x
// 16B (8 bf16). Lane l of frag (s,c): col = c*16+(l&15), k = s*32+(l>>4)*8+i.
// ---------------------------------------------------------------------------
__global__ void prep_kernel(const float* __restrict__ Wf, short* __restrict__ frag) {
  int p = blockIdx.x * blockDim.x + threadIdx.x;  // 0..4095
  if (p >= 4096) return;
  int f = p >> 6, l = p & 63;
  int s = f >> 3, c = f & 7;
  int col = c * 16 + (l & 15);
  int k0 = s * 32 + ((l >> 4) << 3);
  short8 v;
#pragma unroll
  for (int i = 0; i < 8; ++i) v[i] = f2bf(Wf[(k0 + i) * NFn + col]);
  *(short8*)(frag + (size_t)p * 8) = v;
}

// ---------------------------------------------------------------------------
// Main: block = 256 thr = 4 waves; block tile = 128 rows; wave = 32 rows
// (2 row-tiles of 16). Per k-step s (K=32): load A frags straight from global
// (full 128B line per row), leaky_relu in fp32, logit FMAs in fp32, cvt bf16,
// 8 MFMAs per row-tile against LDS B-frags. Epilogue: bias+LN in-register,
// exp(logit)+segment atomics.
// ---------------------------------------------------------------------------
__global__ __launch_bounds__(256) void main_kernel(
    const float* __restrict__ X, const short* __restrict__ fragWS,
    const float* __restrict__ Wa, const float* __restrict__ ba,
    const float* __restrict__ bfeat, const float* __restrict__ gamma,
    const float* __restrict__ beta, const int* __restrict__ res_index,
    float* __restrict__ Nacc, float* __restrict__ D) {
  __shared__ short sB[4096 * 8];  // 64KB exactly

  const int tid = threadIdx.x;
  {  // coalesced copy of B-frag image
    const int4* src = (const int4*)fragWS;
    int4* dst = (int4*)sB;
#pragma unroll 4
    for (int i = tid; i < 4096; i += 256) dst[i] = src[i];
  }
  __syncthreads();

  const int lane = tid & 63;
  const int wv = tid >> 6;
  const int rowbase = blockIdx.x * 128 + wv * 32;
  const int colb = lane & 15;  // col-in-tile and row-in-tile (logit path)
  const int kg = lane >> 4;    // k-group 0..3

  float g_r[8], be_r[8], bi_r[8];
#pragma unroll
  for (int c = 0; c < 8; ++c) {
    int col = c * 16 + colb;
    g_r[c] = gamma[col];
    be_r[c] = beta[col];
    bi_r[c] = bfeat[col];
  }
  const float batn = ba[0];

  f32x4 acc[2][8];
#pragma unroll
  for (int rt = 0; rt < 2; ++rt)
#pragma unroll
    for (int c = 0; c < 8; ++c) acc[rt][c] = (f32x4)(0.0f);
  float logit[2] = {0.f, 0.f};

  int gr0 = rowbase + colb;
  int gr1 = rowbase + 16 + colb;
  long r0 = (gr0 < RFn) ? gr0 : (RFn - 1);
  long r1 = (gr1 < RFn) ? gr1 : (RFn - 1);
  const float* xp0 = X + r0 * F1n + kg * 8;
  const float* xp1 = X + r1 * F1n + kg * 8;

#pragma unroll
  for (int s = 0; s < 8; ++s) {
    short8 bfr[8];
#pragma unroll
    for (int c = 0; c < 8; ++c)
      bfr[c] = *(const short8*)(sB + (((s * 8 + c) * 64 + lane) * 8));
    const float4 wa0 = *(const float4*)(Wa + s * 32 + kg * 8);
    const float4 wa1 = *(const float4*)(Wa + s * 32 + kg * 8 + 4);
#pragma unroll
    for (int rt = 0; rt < 2; ++rt) {
      const float* xp = rt ? xp1 : xp0;
      const float4 x0 = *(const float4*)(xp + s * 32);
      const float4 x1 = *(const float4*)(xp + s * 32 + 4);
      float a0 = fmaxf(x0.x, 0.01f * x0.x);
      float a1 = fmaxf(x0.y, 0.01f * x0.y);
      float a2 = fmaxf(x0.z, 0.01f * x0.z);
      float a3 = fmaxf(x0.w, 0.01f * x0.w);
      float a4 = fmaxf(x1.x, 0.01f * x1.x);
      float a5 = fmaxf(x1.y, 0.01f * x1.y);
      float a6 = fmaxf(x1.z, 0.01f * x1.z);
      float a7 = fmaxf(x1.w, 0.01f * x1.w);
      logit[rt] += a0 * wa0.x + a1 * wa0.y + a2 * wa0.z + a3 * wa0.w +
                   a4 * wa1.x + a5 * wa1.y + a6 * wa1.z + a7 * wa1.w;
      short8 af;
      af[0] = f2bf(a0); af[1] = f2bf(a1); af[2] = f2bf(a2); af[3] = f2bf(a3);
      af[4] = f2bf(a4); af[5] = f2bf(a5); af[6] = f2bf(a6); af[7] = f2bf(a7);
#pragma unroll
      for (int c = 0; c < 8; ++c)
        acc[rt][c] =
            __builtin_amdgcn_mfma_f32_16x16x32_bf16(af, bfr[c], acc[rt][c], 0, 0, 0);
    }
  }

  // ---------------- epilogue ----------------
#pragma unroll
  for (int rt = 0; rt < 2; ++rt) {
    // full logit for row (lane&15) of this row-tile
    float lg = logit[rt];
    lg += __shfl_xor(lg, 16);
    lg += __shfl_xor(lg, 32);
    const float wexp = __expf(lg + batn);
    const int gr = rowbase + rt * 16 + colb;
    const int seg = res_index[(gr < RFn) ? gr : (RFn - 1)];
    if (lane < 16 && gr < RFn) atomicAdd(&D[seg], wexp);

    // redistribute w/seg to the rows this lane's acc elements belong to
    float w4[4];
    int s4[4], v4[4];
#pragma unroll
    for (int reg = 0; reg < 4; ++reg) {
      int srcl = kg * 4 + reg;  // row-in-tile of acc element `reg`
      w4[reg] = __shfl(wexp, srcl);
      s4[reg] = __shfl(seg, srcl);
      v4[reg] = (rowbase + rt * 16 + srcl) < RFn;
    }

    // bias + LayerNorm stats (row = kg*4+reg lives in 16 lanes of group kg)
    float s1[4] = {0.f, 0.f, 0.f, 0.f}, s2[4] = {0.f, 0.f, 0.f, 0.f};
#pragma unroll
    for (int c = 0; c < 8; ++c)
#pragma unroll
      for (int reg = 0; reg < 4; ++reg) {
        float t = acc[rt][c][reg] + bi_r[c];
        acc[rt][c][reg] = t;
        s1[reg] += t;
        s2[reg] += t * t;
      }
#pragma unroll
    for (int off = 1; off <= 8; off <<= 1)
#pragma unroll
      for (int reg = 0; reg < 4; ++reg) {
        s1[reg] += __shfl_xor(s1[reg], off);
        s2[reg] += __shfl_xor(s2[reg], off);
      }
    float mu[4], rs[4];
#pragma unroll
    for (int reg = 0; reg < 4; ++reg) {
      mu[reg] = s1[reg] * (1.0f / NFn);
      float var = s2[reg] * (1.0f / NFn) - mu[reg] * mu[reg];
      rs[reg] = rsqrtf(var + LN_EPSn);
    }

    // scatter: N[seg][col] += feat * w
#pragma unroll
    for (int c = 0; c < 8; ++c)
#pragma unroll
      for (int reg = 0; reg < 4; ++reg) {
        if (v4[reg]) {
          float feat = (acc[rt][c][reg] - mu[reg]) * rs[reg] * g_r[c] + be_r[c];
          atomicAdd(Nacc + (size_t)s4[reg] * NFn + c * 16 + colb, feat * w4[reg]);
        }
      }
  }
}

// out[seg][col] = N/D, 0 for empty segments
__global__ void div_kernel(float* __restrict__ out, const float* __restrict__ D) {
  int i = blockIdx.x * 256 + threadIdx.x;
  if (i < RAn * NFn) {
    float d = D[i >> 7];
    out[i] = (d > 0.f) ? out[i] / d : 0.f;
  }
}

extern "C" void kernel_launch(void* const* d_in, const int* in_sizes, int n_in,
                              void* d_out, int out_size, void* d_ws, size_t ws_size,
                              hipStream_t stream) {
  const float* X = (const float*)d_in[0];
  const float* Wf = (const float*)d_in[1];
  const float* bfeat = (const float*)d_in[2];
  const float* gamma = (const float*)d_in[3];
  const float* beta = (const float*)d_in[4];
  const float* Wa = (const float*)d_in[5];
  const float* ba = (const float*)d_in[6];
  const int* ri = (const int*)d_in[7];
  float* out = (float*)d_out;

  short* frag = (short*)d_ws;                       // 64 KB B-frag image
  float* D = (float*)((char*)d_ws + 65536);         // 50000 f32 denominators

  hipMemsetAsync(d_out, 0, (size_t)RAn * NFn * sizeof(float), stream);
  hipMemsetAsync(D, 0, (size_t)RAn * sizeof(float), stream);

  prep_kernel<<<16, 256, 0, stream>>>(Wf, frag);
  main_kernel<<<(RFn + 127) / 128, 256, 0, stream>>>(X, frag, Wa, ba, bfeat,
                                                     gamma, beta, ri, out, D);
  div_kernel<<<(RAn * NFn + 255) / 256, 256, 0, stream>>>(out, D);
}